// Round 7
// baseline (453.194 us; speedup 1.0000x reference)
//
#include <hip/hip_runtime.h>
#include <hip/hip_bf16.h>
#include <math.h>

typedef __bf16 bf16_t;
typedef __bf16 bf16x8 __attribute__((ext_vector_type(8)));
typedef float floatx4 __attribute__((ext_vector_type(4)));

#define T_TOK 2048
#define HID 2048
#define NH 16
#define D_NOPE 128
#define D_ROPE 64
#define D_QK 192
#define D_V 128
#define Q_LORA 1536
#define KV_LORA 512
#define QKV_N 2112            // 1536+512+64
#define QKV_NPAD 2176         // padded to 17*128
#define SCALING 0.07216878364870323f
#define LOG2E 1.442695041f
#define PS_STRIDE 76          // p_s row stride: quads hit disjoint bank groups

#define MFMA_BF16(a, b, c) __builtin_amdgcn_mfma_f32_16x16x32_bf16(a, b, c, 0, 0, 0)

// async 16B global->LDS (verified m97 pattern; LDS dest must be lane-linear)
__device__ __forceinline__ void gload16(const void* g, void* l) {
    __builtin_amdgcn_global_load_lds(
        (const __attribute__((address_space(1))) unsigned int*)g,
        (__attribute__((address_space(3))) unsigned int*)l, 16, 0, 0);
}

// ---------------------------------------------------------------------------
// MFMA GEMM: C[M,N] = A[M,K] * Bt[N,K]^T, 128x128 tile, BK=64.
// MODE 0: fp32 C. MODE 1: bf16 C. MODE 2: kv-split epilogue.  (unchanged r6)
// ---------------------------------------------------------------------------
template <int MODE>
__global__ __launch_bounds__(256) void gemm_mfma(
    const bf16_t* __restrict__ A, const bf16_t* __restrict__ Bt,
    float* __restrict__ Cf, bf16_t* __restrict__ Cb,
    bf16_t* __restrict__ knope, bf16_t* __restrict__ vtmp,
    int M, int N, int K)
{
    __shared__ __align__(16) bf16_t As[2 * 128 * 32];
    __shared__ __align__(16) bf16_t Bs[2 * 128 * 32];
    const int tid = threadIdx.x;
    const int lane = tid & 63;
    const int w = tid >> 6;
    const int wm = w >> 1, wn = w & 1;
    const int m0 = blockIdx.y * 128, n0 = blockIdx.x * 128;
    const int l15 = lane & 15, quad = lane >> 4;

    floatx4 acc[4][4] = {};

    for (int k0 = 0; k0 < K; k0 += 64) {
#pragma unroll
        for (int it = 0; it < 4; ++it) {
            int slot = it * 256 + tid;
            int kk2 = slot >> 9;
            int r = (slot >> 2) & 127;
            int c = slot & 3;
            gload16((const char*)(A + (size_t)(m0 + r) * K + k0 + kk2 * 32 + c * 8),
                    (char*)As + slot * 16);
            gload16((const char*)(Bt + (size_t)(n0 + r) * K + k0 + kk2 * 32 + c * 8),
                    (char*)Bs + slot * 16);
        }
        __syncthreads();
#pragma unroll
        for (int kk2 = 0; kk2 < 2; ++kk2) {
            bf16x8 af[4], bfr[4];
#pragma unroll
            for (int mi = 0; mi < 4; ++mi)
                af[mi] = *(const bf16x8*)(As + kk2 * 4096 +
                                          (wm * 64 + mi * 16 + l15) * 32 + quad * 8);
#pragma unroll
            for (int ni = 0; ni < 4; ++ni)
                bfr[ni] = *(const bf16x8*)(Bs + kk2 * 4096 +
                                           (wn * 64 + ni * 16 + l15) * 32 + quad * 8);
#pragma unroll
            for (int mi = 0; mi < 4; ++mi)
#pragma unroll
                for (int ni = 0; ni < 4; ++ni)
                    acc[mi][ni] = MFMA_BF16(af[mi], bfr[ni], acc[mi][ni]);
        }
        __syncthreads();
    }

#pragma unroll
    for (int mi = 0; mi < 4; ++mi)
#pragma unroll
        for (int ni = 0; ni < 4; ++ni)
#pragma unroll
            for (int r = 0; r < 4; ++r) {
                int row = m0 + wm * 64 + mi * 16 + quad * 4 + r;
                int col = n0 + wn * 64 + ni * 16 + l15;
                float v = acc[mi][ni][r];
                if (MODE == 0) {
                    Cf[(size_t)row * N + col] = v;
                } else if (MODE == 1) {
                    Cb[(size_t)row * N + col] = (bf16_t)v;
                } else {
                    int h = col >> 8, dd = col & 255;
                    if (dd < 128)
                        knope[((size_t)h * T_TOK + row) * 128 + dd] = (bf16_t)v;
                    else
                        vtmp[(size_t)row * 2048 + h * 128 + (dd - 128)] = (bf16_t)v;
                }
            }
}

// ---------------------------------------------------------------------------
// Fused weight prep / transposes / cvt (unchanged r6)
// ---------------------------------------------------------------------------
__global__ void transpose_all(const float* __restrict__ w0, const float* __restrict__ w1,
                              const float* __restrict__ w2, const float* __restrict__ w3,
                              bf16_t* __restrict__ o0, bf16_t* __restrict__ o1,
                              bf16_t* __restrict__ o2, bf16_t* __restrict__ o3) {
    const float* in; bf16_t* out; int K, N;
    switch (blockIdx.z) {
        case 0: in = w0; out = o0; K = 2048; N = 2112; break;
        case 1: in = w1; out = o1; K = 1536; N = 3072; break;
        case 2: in = w2; out = o2; K = 512;  N = 4096; break;
        default: in = w3; out = o3; K = 2048; N = 2048; break;
    }
    int n0 = blockIdx.x * 32, k0 = blockIdx.y * 32;
    if (n0 >= N || k0 >= K) return;
    __shared__ float tile[32][33];
    int tx = threadIdx.x, ty = threadIdx.y;
    for (int i = ty; i < 32; i += 8)
        tile[i][tx] = in[(size_t)(k0 + i) * N + n0 + tx];
    __syncthreads();
    for (int i = ty; i < 32; i += 8)
        out[(size_t)(n0 + i) * K + k0 + tx] = (bf16_t)tile[tx][i];
}

__global__ void transpose_b2b(const bf16_t* __restrict__ in, bf16_t* __restrict__ out,
                              int R, int C) {
    __shared__ bf16_t tile[32][33];
    int c0 = blockIdx.x * 32, r0 = blockIdx.y * 32;
    int tx = threadIdx.x, ty = threadIdx.y;
    for (int i = ty; i < 32; i += 8)
        tile[i][tx] = in[(size_t)(r0 + i) * C + c0 + tx];
    __syncthreads();
    for (int i = ty; i < 32; i += 8)
        out[(size_t)(c0 + i) * R + r0 + tx] = tile[tx][i];
}

__global__ void cvt_f2b(const float* __restrict__ in, bf16_t* __restrict__ out, int n) {
    int i = blockIdx.x * 256 + threadIdx.x;
    if (i < n) out[i] = (bf16_t)in[i];
}

// ---------------------------------------------------------------------------
// Fused mid-stage (unchanged r6)
// ---------------------------------------------------------------------------
__global__ void mid_fuse(const float* __restrict__ qkv_a, const int* __restrict__ pos,
                         const float* __restrict__ g_q, const float* __restrict__ g_kv,
                         bf16_t* __restrict__ qn, bf16_t* __restrict__ kvn,
                         bf16_t* __restrict__ kpe) {
    int t = blockIdx.x, tid = threadIdx.x;
    const float* x = qkv_a + (size_t)t * QKV_NPAD;
    __shared__ float red[256];
    float ss = 0.f;
    for (int c = tid; c < Q_LORA; c += 256) { float v = x[c]; ss += v * v; }
    red[tid] = ss;
    __syncthreads();
    for (int o = 128; o > 0; o >>= 1) {
        if (tid < o) red[tid] += red[tid + o];
        __syncthreads();
    }
    float rq = rsqrtf(red[0] / (float)Q_LORA + 1e-6f);
    __syncthreads();
    ss = 0.f;
    for (int c = Q_LORA + tid; c < Q_LORA + KV_LORA; c += 256) { float v = x[c]; ss += v * v; }
    red[tid] = ss;
    __syncthreads();
    for (int o = 128; o > 0; o >>= 1) {
        if (tid < o) red[tid] += red[tid + o];
        __syncthreads();
    }
    float rkv = rsqrtf(red[0] / (float)KV_LORA + 1e-6f);

    for (int c = tid; c < Q_LORA; c += 256)
        qn[(size_t)t * Q_LORA + c] = (bf16_t)(x[c] * rq * g_q[c]);
    for (int c = tid; c < KV_LORA; c += 256)
        kvn[(size_t)t * KV_LORA + c] = (bf16_t)(x[Q_LORA + c] * rkv * g_kv[c]);

    if (tid < 32) {
        int i = tid;
        double inv = pow(10000.0, -(double)(2 * i) / 64.0);
        double fd = (double)pos[t] * inv;
        float c = (float)cos(fd), s = (float)sin(fd);
        float x1 = x[Q_LORA + KV_LORA + 2 * i], x2 = x[Q_LORA + KV_LORA + 2 * i + 1];
        kpe[t * 64 + 2 * i] = (bf16_t)(x1 * c - x2 * s);
        kpe[t * 64 + 2 * i + 1] = (bf16_t)(x1 * s + x2 * c);
    }
}

__global__ void rope_q_kernel(bf16_t* __restrict__ q, const int* __restrict__ pos) {
    int idx = blockIdx.x * blockDim.x + threadIdx.x;
    if (idx >= T_TOK * NH * 32) return;
    int i = idx & 31;
    int h = (idx >> 5) & (NH - 1);
    int t = idx >> 9;
    double inv = pow(10000.0, -(double)(2 * i) / 64.0);
    double fd = (double)pos[t] * inv;
    float c = (float)cos(fd), s = (float)sin(fd);
    bf16_t* base = q + (size_t)t * (NH * D_QK) + h * D_QK + D_NOPE;
    float x1 = (float)base[2 * i], x2 = (float)base[2 * i + 1];
    base[2 * i] = (bf16_t)(x1 * c - x2 * s);
    base[2 * i + 1] = (bf16_t)(x1 * s + x2 * c);
}

// ---------------------------------------------------------------------------
// Flash attention v4 — split-s (flash-decoding) partials.
// 1024 blocks: id -> h = id&15, qt = 31-((id>>4)&31), chunk c = id>>9.
// Chunk 0 handles s-tiles [0, h0), chunk 1 [h0, qt+1), h0 = (qt+2)>>1.
// LDS: kn dbuf 32 KB + p_s 9.5 KB = 41.5 KB -> 3 blocks/CU. V + kpe B-frags
// load direct from global (L2-hot; addresses independent of softmax -> hoist).
// Partials: o unnormalized (bf16), m/l fp32. Combine kernel normalizes.
// ---------------------------------------------------------------------------
__global__ __launch_bounds__(256, 3) void attn_part(
    const bf16_t* __restrict__ qbuf, const bf16_t* __restrict__ knope,
    const bf16_t* __restrict__ kpe, const bf16_t* __restrict__ vT,
    bf16_t* __restrict__ o_part, float* __restrict__ ml)
{
    const int id = blockIdx.x;
    const int h = id & 15;
    const int qt = 31 - ((id >> 4) & 31);
    const int c = id >> 9;
    const int q0 = qt * 64;
    const int h0 = (qt + 2) >> 1;
    const int sBeg = c ? h0 : 0;
    const int sEnd = c ? (qt + 1) : h0;
    const int tile = qt * 16 + h;
    const int tid = threadIdx.x, lane = tid & 63, w = tid >> 6;
    const int l15 = lane & 15, quad = lane >> 4;

    __shared__ __align__(16) bf16_t kn2[2][4 * 64 * 32];       // 32 KB
    __shared__ __align__(16) bf16_t p_s[64 * PS_STRIDE];       // 9.5 KB

    floatx4 o[8] = {};
    float mrow[4], lrow[4];
#pragma unroll
    for (int r = 0; r < 4; ++r) { mrow[r] = -3.0e38f; lrow[r] = 0.f; }

    if (sBeg < sEnd) {
        // Q fragments (wave w owns q-rows [q0+w*16, q0+w*16+16))
        bf16x8 qf[6];
        {
            const bf16_t* qp = qbuf + (size_t)(q0 + w * 16 + l15) * (NH * D_QK) + h * D_QK;
#pragma unroll
            for (int kk = 0; kk < 6; ++kk)
                qf[kk] = *(const bf16x8*)(qp + kk * 32 + quad * 8);
        }

#define STAGE_KN(buf, s0)                                                                \
        do {                                                                             \
            _Pragma("unroll")                                                            \
            for (int it = 0; it < 4; ++it) {                                             \
                int slot = it * 256 + tid;                                               \
                int s = (slot >> 2) & 63, cc = slot & 3, kk = slot >> 8;                 \
                gload16((const char*)(knope + ((size_t)h * T_TOK + (s0) + s) * 128 +     \
                                      kk * 32 + cc * 8),                                 \
                        (char*)kn2[buf] + slot * 16);                                    \
            }                                                                            \
        } while (0)

        STAGE_KN(0, sBeg * 64);

        for (int si = sBeg; si < sEnd; ++si) {
            const int s0 = si * 64;
            const int buf = (si - sBeg) & 1;
            __syncthreads();                                    // drain this tile's kn
            if (si + 1 < sEnd) STAGE_KN(buf ^ 1, s0 + 64);      // prefetch next

            // ---- kpe B-frags direct from global/L2 ----
            bf16x8 peF[4][2];
#pragma unroll
            for (int ni = 0; ni < 4; ++ni)
#pragma unroll
                for (int kk = 0; kk < 2; ++kk)
                    peF[ni][kk] = *(const bf16x8*)(kpe + (size_t)(s0 + ni * 16 + l15) * 64 +
                                                   kk * 32 + quad * 8);

            // ---- S = Q K^T ----
            floatx4 s_acc[4] = {};
#pragma unroll
            for (int ni = 0; ni < 4; ++ni) {
#pragma unroll
                for (int kk = 0; kk < 4; ++kk) {
                    bf16x8 b = *(const bf16x8*)(kn2[buf] + (kk * 64 + ni * 16 + l15) * 32 + quad * 8);
                    s_acc[ni] = MFMA_BF16(qf[kk], b, s_acc[ni]);
                }
#pragma unroll
                for (int kk = 0; kk < 2; ++kk)
                    s_acc[ni] = MFMA_BF16(qf[4 + kk], peF[ni][kk], s_acc[ni]);
            }

            const bool diag = (si == qt);
#pragma unroll
            for (int ni = 0; ni < 4; ++ni)
#pragma unroll
                for (int r = 0; r < 4; ++r) {
                    float v = s_acc[ni][r] * SCALING;
                    if (diag && (ni * 16 + l15) > (w * 16 + quad * 4 + r)) v = -3.0e38f;
                    s_acc[ni][r] = v;
                }

            // ---- online softmax (rows in 16-lane groups) ----
            float alpha[4], tsum[4];
#pragma unroll
            for (int r = 0; r < 4; ++r) {
                float mx = fmaxf(fmaxf(s_acc[0][r], s_acc[1][r]),
                                 fmaxf(s_acc[2][r], s_acc[3][r]));
                mx = fmaxf(mx, __shfl_xor(mx, 1, 64));
                mx = fmaxf(mx, __shfl_xor(mx, 2, 64));
                mx = fmaxf(mx, __shfl_xor(mx, 4, 64));
                mx = fmaxf(mx, __shfl_xor(mx, 8, 64));
                float mnew = fmaxf(mrow[r], mx);
                alpha[r] = exp2f((mrow[r] - mnew) * LOG2E);
                mrow[r] = mnew;
                tsum[r] = 0.f;
            }
#pragma unroll
            for (int ni = 0; ni < 4; ++ni)
#pragma unroll
                for (int r = 0; r < 4; ++r) {
                    float pv = exp2f((s_acc[ni][r] - mrow[r]) * LOG2E);
                    tsum[r] += pv;
                    p_s[(w * 16 + quad * 4 + r) * PS_STRIDE + ni * 16 + l15] = (bf16_t)pv;
                }
#pragma unroll
            for (int r = 0; r < 4; ++r) {
                float s = tsum[r];
                s += __shfl_xor(s, 1, 64);
                s += __shfl_xor(s, 2, 64);
                s += __shfl_xor(s, 4, 64);
                s += __shfl_xor(s, 8, 64);
                lrow[r] = lrow[r] * alpha[r] + s;
            }
#pragma unroll
            for (int ni = 0; ni < 8; ++ni)
#pragma unroll
                for (int r = 0; r < 4; ++r) o[ni][r] *= alpha[r];

            // ---- O += P V  (P rows wave-private; V direct from global/L2) ----
#pragma unroll
            for (int ks = 0; ks < 2; ++ks) {
                bf16x8 a = *(const bf16x8*)(p_s + (w * 16 + l15) * PS_STRIDE + ks * 32 + quad * 8);
#pragma unroll
                for (int ni = 0; ni < 8; ++ni) {
                    bf16x8 b = *(const bf16x8*)(vT + ((size_t)h * 128 + ni * 16 + l15) * T_TOK +
                                                s0 + ks * 32 + quad * 8);
                    o[ni] = MFMA_BF16(a, b, o[ni]);
                }
            }
        }
#undef STAGE_KN
    }

    // ---- write partials (o unnormalized bf16; m/l fp32) ----
    const size_t pbase = ((size_t)c * 512 + tile) * 64;
#pragma unroll
    for (int ni = 0; ni < 8; ++ni)
#pragma unroll
        for (int r = 0; r < 4; ++r) {
            int row = w * 16 + quad * 4 + r;
            o_part[(pbase + row) * 128 + ni * 16 + l15] = (bf16_t)o[ni][r];
        }
    if (l15 == 0) {
#pragma unroll
        for (int r = 0; r < 4; ++r) {
            int row = w * 16 + quad * 4 + r;
            ml[(pbase + row) * 2 + 0] = mrow[r];
            ml[(pbase + row) * 2 + 1] = lrow[r];
        }
    }
}

// ---------------------------------------------------------------------------
// Combine: attn_o[t][h*128+d] = sum_c e^{m_c-m*} o_c / sum_c e^{m_c-m*} l_c
// One thread per 8 output cols.
// ---------------------------------------------------------------------------
__global__ void attn_combine(const bf16_t* __restrict__ o_part,
                             const float* __restrict__ ml,
                             bf16_t* __restrict__ attn_o)
{
    int idx = blockIdx.x * 256 + threadIdx.x;    // t*256 + col-group
    int t = idx >> 8, cg = idx & 255;
    int col = cg * 8;
    int h = col >> 7;
    int qt = t >> 6, r = t & 63;
    size_t tile = (size_t)qt * 16 + h;
    size_t p0 = (tile)*64 + r, p1 = (512 + tile) * 64 + r;
    float m0 = ml[p0 * 2], l0 = ml[p0 * 2 + 1];
    float m1 = ml[p1 * 2], l1 = ml[p1 * 2 + 1];
    float mx = fmaxf(m0, m1);
    float e0 = (l0 > 0.f) ? exp2f((m0 - mx) * LOG2E) : 0.f;
    float e1 = (l1 > 0.f) ? exp2f((m1 - mx) * LOG2E) : 0.f;
    float inv = 1.f / (e0 * l0 + e1 * l1);
    int d = col & 127;
    bf16x8 a0 = *(const bf16x8*)(o_part + p0 * 128 + d);
    bf16x8 a1 = *(const bf16x8*)(o_part + p1 * 128 + d);
    bf16x8 out;
#pragma unroll
    for (int j = 0; j < 8; ++j)
        out[j] = (bf16_t)((e0 * (float)a0[j] + e1 * (float)a1[j]) * inv);
    *(bf16x8*)(attn_o + (size_t)t * (NH * D_V) + col) = out;
}

// ---------------------------------------------------------------------------
extern "C" void kernel_launch(void* const* d_in, const int* in_sizes, int n_in,
                              void* d_out, int out_size, void* d_ws, size_t ws_size,
                              hipStream_t stream) {
    const float* hidden = (const float*)d_in[0];
    const int* positions = (const int*)d_in[1];
    const float* w_qkv_a = (const float*)d_in[2];
    const float* g_q = (const float*)d_in[3];
    const float* w_q_b = (const float*)d_in[4];
    const float* g_kv = (const float*)d_in[5];
    const float* w_kv_b = (const float*)d_in[6];
    const float* w_o = (const float*)d_in[7];
    float* out = (float*)d_out;

    // ---- workspace layout (~95 MB, same footprint as r4-r6) ----
    char* p = (char*)d_ws;
    float* qkv_a = (float*)p;                       // [2048][2176] fp32
    bf16_t* attn_o = (bf16_t*)p;                    // alias (qkv_a dead by then)
    p += (size_t)T_TOK * QKV_NPAD * 4;
    bf16_t* hbf = (bf16_t*)p;                       // [2048][2048] bf16
    bf16_t* qn = hbf;                               // alias after GEMM1
    bf16_t* kvn = hbf + (size_t)T_TOK * Q_LORA;
    p += (size_t)T_TOK * HID * 2;
    bf16_t* qbuf = (bf16_t*)p;  p += (size_t)T_TOK * NH * D_QK * 2;   // [2048][3072]
    bf16_t* vtmp = (bf16_t*)p;  p += (size_t)T_TOK * NH * D_V * 2;    // [2048][2048]
    bf16_t* knope = (bf16_t*)p; p += (size_t)NH * T_TOK * 128 * 2;    // [16][2048][128]
    bf16_t* vT = (bf16_t*)p;    p += (size_t)NH * 128 * T_TOK * 2;    // [16][128][2048]
    bf16_t* kpe = (bf16_t*)p;   p += (size_t)T_TOK * 64 * 2;          // [2048][64]
    bf16_t* wt_qkv_a = (bf16_t*)p; p += (size_t)QKV_NPAD * HID * 2;   // [2176][2048] 8.9MB
    bf16_t* wt_q_b = (bf16_t*)p;   p += (size_t)3072 * Q_LORA * 2;    // [3072][1536] 9.4MB
    bf16_t* wt_kv_b = (bf16_t*)p;  p += (size_t)4096 * KV_LORA * 2;   // [4096][512]
    bf16_t* wt_o = (bf16_t*)p;                                        // [2048][2048]

    // attn partials OVERLAY wt_qkv_a + wt_q_b (both dead before attn):
    //   o_part bf16 [2][512][64][128] = 16.78 MB ; ml fp32 [2][512][64][2] = 0.5 MB
    bf16_t* o_part = wt_qkv_a;
    float* ml = (float*)(o_part + (size_t)2 * 512 * 64 * 128);

    dim3 tb(32, 8);

    // 0. dtype prep
    cvt_f2b<<<(T_TOK * HID) / 256, 256, 0, stream>>>(hidden, hbf, T_TOK * HID);
    transpose_all<<<dim3(128, 64, 4), tb, 0, stream>>>(
        w_qkv_a, w_q_b, w_kv_b, w_o, wt_qkv_a, wt_q_b, wt_kv_b, wt_o);

    // 1. qkv_a = hidden @ w_qkv_a
    gemm_mfma<0><<<dim3(QKV_NPAD / 128, T_TOK / 128), 256, 0, stream>>>(
        hbf, wt_qkv_a, qkv_a, nullptr, nullptr, nullptr, T_TOK, QKV_NPAD, HID);

    // 2. fused rmsnorm + gains + rope(k_pe)
    mid_fuse<<<T_TOK, 256, 0, stream>>>(qkv_a, positions, g_q, g_kv, qn, kvn, kpe);

    // 3. q = qn @ w_q_b ; rope in place   (wt_qkv_a dead after gemm1)
    gemm_mfma<1><<<dim3(3072 / 128, T_TOK / 128), 256, 0, stream>>>(
        qn, wt_q_b, nullptr, qbuf, nullptr, nullptr, T_TOK, 3072, Q_LORA);
    rope_q_kernel<<<(T_TOK * NH * 32) / 256, 256, 0, stream>>>(qbuf, positions);

    // 4. kv GEMM with split epilogue -> knope + vtmp; vtmp -> vT  (wt_q_b dead after)
    gemm_mfma<2><<<dim3(4096 / 128, T_TOK / 128), 256, 0, stream>>>(
        kvn, wt_kv_b, nullptr, nullptr, knope, vtmp, T_TOK, 4096, KV_LORA);
    transpose_b2b<<<dim3(HID / 32, T_TOK / 32), tb, 0, stream>>>(vtmp, vT, T_TOK, HID);

    // 5. flash attention: split-s partials (1024 blocks) + combine
    attn_part<<<1024, 256, 0, stream>>>(qbuf, knope, kpe, vT, o_part, ml);
    attn_combine<<<(T_TOK * 256) / 256, 256, 0, stream>>>(o_part, ml, attn_o);

    // 6. out = attn_o @ w_o
    gemm_mfma<0><<<dim3(HID / 128, T_TOK / 128), 256, 0, stream>>>(
        attn_o, wt_o, out, nullptr, nullptr, nullptr, T_TOK, HID, NH * D_V);
}

// Round 8
// 377.318 us; speedup vs baseline: 1.2011x; 1.2011x over previous
//
#include <hip/hip_runtime.h>
#include <hip/hip_bf16.h>
#include <math.h>

typedef __bf16 bf16_t;
typedef __bf16 bf16x8 __attribute__((ext_vector_type(8)));
typedef float floatx4 __attribute__((ext_vector_type(4)));

#define T_TOK 2048
#define HID 2048
#define NH 16
#define D_NOPE 128
#define D_ROPE 64
#define D_QK 192
#define D_V 128
#define Q_LORA 1536
#define KV_LORA 512
#define QKV_N 2112            // 1536+512+64
#define QKV_NPAD 2176         // padded to 17*128
#define SCALING 0.07216878364870323f
#define LOG2E 1.442695041f
#define EXP_C1 (SCALING * LOG2E)      // score -> exp2 arg scale
#define EXP_C2 (12.0f * LOG2E)        // fixed bias (replaces online max; safe to s~100)

#define MFMA_BF16(a, b, c) __builtin_amdgcn_mfma_f32_16x16x32_bf16(a, b, c, 0, 0, 0)

// async 16B global->LDS (verified m97 pattern; LDS dest must be lane-linear)
__device__ __forceinline__ void gload16(const void* g, void* l) {
    __builtin_amdgcn_global_load_lds(
        (const __attribute__((address_space(1))) unsigned int*)g,
        (__attribute__((address_space(3))) unsigned int*)l, 16, 0, 0);
}

// ---------------------------------------------------------------------------
// MFMA GEMM: C[M,N] = A[M,K] * Bt[N,K]^T, 128x128 tile, BK=64.
// MODE 0: fp32 C. MODE 1: bf16 C. MODE 2: kv-split epilogue (kfull 192-stride).
// ---------------------------------------------------------------------------
template <int MODE>
__global__ __launch_bounds__(256) void gemm_mfma(
    const bf16_t* __restrict__ A, const bf16_t* __restrict__ Bt,
    float* __restrict__ Cf, bf16_t* __restrict__ Cb,
    bf16_t* __restrict__ kfull, bf16_t* __restrict__ vtmp,
    int M, int N, int K)
{
    __shared__ __align__(16) bf16_t As[2 * 128 * 32];
    __shared__ __align__(16) bf16_t Bs[2 * 128 * 32];
    const int tid = threadIdx.x;
    const int lane = tid & 63;
    const int w = tid >> 6;
    const int wm = w >> 1, wn = w & 1;
    const int m0 = blockIdx.y * 128, n0 = blockIdx.x * 128;
    const int l15 = lane & 15, quad = lane >> 4;

    floatx4 acc[4][4] = {};

    for (int k0 = 0; k0 < K; k0 += 64) {
#pragma unroll
        for (int it = 0; it < 4; ++it) {
            int slot = it * 256 + tid;
            int kk2 = slot >> 9;
            int r = (slot >> 2) & 127;
            int c = slot & 3;
            gload16((const char*)(A + (size_t)(m0 + r) * K + k0 + kk2 * 32 + c * 8),
                    (char*)As + slot * 16);
            gload16((const char*)(Bt + (size_t)(n0 + r) * K + k0 + kk2 * 32 + c * 8),
                    (char*)Bs + slot * 16);
        }
        __syncthreads();
#pragma unroll
        for (int kk2 = 0; kk2 < 2; ++kk2) {
            bf16x8 af[4], bfr[4];
#pragma unroll
            for (int mi = 0; mi < 4; ++mi)
                af[mi] = *(const bf16x8*)(As + kk2 * 4096 +
                                          (wm * 64 + mi * 16 + l15) * 32 + quad * 8);
#pragma unroll
            for (int ni = 0; ni < 4; ++ni)
                bfr[ni] = *(const bf16x8*)(Bs + kk2 * 4096 +
                                           (wn * 64 + ni * 16 + l15) * 32 + quad * 8);
#pragma unroll
            for (int mi = 0; mi < 4; ++mi)
#pragma unroll
                for (int ni = 0; ni < 4; ++ni)
                    acc[mi][ni] = MFMA_BF16(af[mi], bfr[ni], acc[mi][ni]);
        }
        __syncthreads();
    }

#pragma unroll
    for (int mi = 0; mi < 4; ++mi)
#pragma unroll
        for (int ni = 0; ni < 4; ++ni)
#pragma unroll
            for (int r = 0; r < 4; ++r) {
                int row = m0 + wm * 64 + mi * 16 + quad * 4 + r;
                int col = n0 + wn * 64 + ni * 16 + l15;
                float v = acc[mi][ni][r];
                if (MODE == 0) {
                    Cf[(size_t)row * N + col] = v;
                } else if (MODE == 1) {
                    Cb[(size_t)row * N + col] = (bf16_t)v;
                } else {
                    int h = col >> 8, dd = col & 255;
                    if (dd < 128)
                        kfull[((size_t)h * T_TOK + row) * 192 + dd] = (bf16_t)v;
                    else
                        vtmp[(size_t)row * 2048 + h * 128 + (dd - 128)] = (bf16_t)v;
                }
            }
}

// ---------------------------------------------------------------------------
// Weight prep / transposes / cvt (unchanged)
// ---------------------------------------------------------------------------
__global__ void transpose_all(const float* __restrict__ w0, const float* __restrict__ w1,
                              const float* __restrict__ w2, const float* __restrict__ w3,
                              bf16_t* __restrict__ o0, bf16_t* __restrict__ o1,
                              bf16_t* __restrict__ o2, bf16_t* __restrict__ o3) {
    const float* in; bf16_t* out; int K, N;
    switch (blockIdx.z) {
        case 0: in = w0; out = o0; K = 2048; N = 2112; break;
        case 1: in = w1; out = o1; K = 1536; N = 3072; break;
        case 2: in = w2; out = o2; K = 512;  N = 4096; break;
        default: in = w3; out = o3; K = 2048; N = 2048; break;
    }
    int n0 = blockIdx.x * 32, k0 = blockIdx.y * 32;
    if (n0 >= N || k0 >= K) return;
    __shared__ float tile[32][33];
    int tx = threadIdx.x, ty = threadIdx.y;
    for (int i = ty; i < 32; i += 8)
        tile[i][tx] = in[(size_t)(k0 + i) * N + n0 + tx];
    __syncthreads();
    for (int i = ty; i < 32; i += 8)
        out[(size_t)(n0 + i) * K + k0 + tx] = (bf16_t)tile[tx][i];
}

__global__ void transpose_b2b(const bf16_t* __restrict__ in, bf16_t* __restrict__ out,
                              int R, int C) {
    __shared__ bf16_t tile[32][33];
    int c0 = blockIdx.x * 32, r0 = blockIdx.y * 32;
    int tx = threadIdx.x, ty = threadIdx.y;
    for (int i = ty; i < 32; i += 8)
        tile[i][tx] = in[(size_t)(r0 + i) * C + c0 + tx];
    __syncthreads();
    for (int i = ty; i < 32; i += 8)
        out[(size_t)(c0 + i) * R + r0 + tx] = tile[tx][i];
}

__global__ void cvt_f2b(const float* __restrict__ in, bf16_t* __restrict__ out, int n) {
    int i = blockIdx.x * 256 + threadIdx.x;
    if (i < n) out[i] = (bf16_t)in[i];
}

// ---------------------------------------------------------------------------
// Fused mid-stage: rms scales + gains -> qn/kvn (bf16); rope(k_pe) broadcast
// into kfull[h][t][128..192) for ALL 16 heads.
// ---------------------------------------------------------------------------
__global__ void mid_fuse(const float* __restrict__ qkv_a, const int* __restrict__ pos,
                         const float* __restrict__ g_q, const float* __restrict__ g_kv,
                         bf16_t* __restrict__ qn, bf16_t* __restrict__ kvn,
                         bf16_t* __restrict__ kfull) {
    int t = blockIdx.x, tid = threadIdx.x;
    const float* x = qkv_a + (size_t)t * QKV_NPAD;
    __shared__ float red[256];
    float ss = 0.f;
    for (int c = tid; c < Q_LORA; c += 256) { float v = x[c]; ss += v * v; }
    red[tid] = ss;
    __syncthreads();
    for (int o = 128; o > 0; o >>= 1) {
        if (tid < o) red[tid] += red[tid + o];
        __syncthreads();
    }
    float rq = rsqrtf(red[0] / (float)Q_LORA + 1e-6f);
    __syncthreads();
    ss = 0.f;
    for (int c = Q_LORA + tid; c < Q_LORA + KV_LORA; c += 256) { float v = x[c]; ss += v * v; }
    red[tid] = ss;
    __syncthreads();
    for (int o = 128; o > 0; o >>= 1) {
        if (tid < o) red[tid] += red[tid + o];
        __syncthreads();
    }
    float rkv = rsqrtf(red[0] / (float)KV_LORA + 1e-6f);

    for (int c = tid; c < Q_LORA; c += 256)
        qn[(size_t)t * Q_LORA + c] = (bf16_t)(x[c] * rq * g_q[c]);
    for (int c = tid; c < KV_LORA; c += 256)
        kvn[(size_t)t * KV_LORA + c] = (bf16_t)(x[Q_LORA + c] * rkv * g_kv[c]);

    if (tid < 32) {
        int i = tid;
        double inv = pow(10000.0, -(double)(2 * i) / 64.0);
        double fd = (double)pos[t] * inv;
        float c = (float)cos(fd), s = (float)sin(fd);
        float x1 = x[Q_LORA + KV_LORA + 2 * i], x2 = x[Q_LORA + KV_LORA + 2 * i + 1];
        bf16_t v0 = (bf16_t)(x1 * c - x2 * s);
        bf16_t v1 = (bf16_t)(x1 * s + x2 * c);
#pragma unroll
        for (int h = 0; h < NH; ++h) {
            kfull[((size_t)h * T_TOK + t) * 192 + 128 + 2 * i] = v0;
            kfull[((size_t)h * T_TOK + t) * 192 + 128 + 2 * i + 1] = v1;
        }
    }
}

__global__ void rope_q_kernel(bf16_t* __restrict__ q, const int* __restrict__ pos) {
    int idx = blockIdx.x * blockDim.x + threadIdx.x;
    if (idx >= T_TOK * NH * 32) return;
    int i = idx & 31;
    int h = (idx >> 5) & (NH - 1);
    int t = idx >> 9;
    double inv = pow(10000.0, -(double)(2 * i) / 64.0);
    double fd = (double)pos[t] * inv;
    float c = (float)cos(fd), s = (float)sin(fd);
    bf16_t* base = q + (size_t)t * (NH * D_QK) + h * D_QK + D_NOPE;
    float x1 = (float)base[2 * i], x2 = (float)base[2 * i + 1];
    base[2 * i] = (bf16_t)(x1 * c - x2 * s);
    base[2 * i + 1] = (bf16_t)(x1 * s + x2 * c);
}

// ---------------------------------------------------------------------------
// Flash attention v5 — shuffle-free, fixed-bias softmax, split-s.
// Block = (qt, h, chunk): 128-row q-tile, chunk = half of the s-range (qt+1
// s-tiles each — exactly equal). id mapping pairs long+short chunks per CU.
// 4 waves x 2 row-strips; B-frags shared across strips (half the LDS reads
// per MFMA). Row-sums l via MFMA with constant ones B-frag (no shuffles).
// LDS: kfull dbuf 48K + vt 16K + p_s 16K (XOR-swizzled) = 80 KB -> 2 blk/CU.
// ---------------------------------------------------------------------------
__global__ __launch_bounds__(256, 2) void attn_part(
    const bf16_t* __restrict__ qbuf, const bf16_t* __restrict__ kfull,
    const bf16_t* __restrict__ vT,
    bf16_t* __restrict__ o_part, float* __restrict__ l_part)
{
    const int id = blockIdx.x;
    int qt, h, c;
    if (id < 256) { c = 0; qt = 15 - (id >> 4); h = id & 15; }
    else          { c = 1; qt = (id - 256) >> 4; h = id & 15; }
    const int q0 = qt * 128;
    const int nHalf = qt + 1;
    const int sBeg = c * nHalf, sEnd = sBeg + nHalf;
    const int unit = qt * 16 + h;
    const int tid = threadIdx.x, lane = tid & 63, w = tid >> 6;
    const int l15 = lane & 15, quad = lane >> 4;

    __shared__ __align__(16) bf16_t kn2[2][6 * 64 * 32];   // 48 KB (K incl. pe)
    __shared__ __align__(16) bf16_t vt2[2 * 128 * 32];     // 16 KB
    __shared__ __align__(16) bf16_t p_s[128 * 64];         // 16 KB, swizzled

    // Q fragments: 2 strips x 6 k-steps (rows q0 + w*32 + st*16 + l15)
    bf16x8 qf[2][6];
#pragma unroll
    for (int st = 0; st < 2; ++st) {
        const bf16_t* qp = qbuf + (size_t)(q0 + w * 32 + st * 16 + l15) * (NH * D_QK) +
                           h * D_QK;
#pragma unroll
        for (int kk = 0; kk < 6; ++kk)
            qf[st][kk] = *(const bf16x8*)(qp + kk * 32 + quad * 8);
    }

    bf16x8 ones;
#pragma unroll
    for (int j = 0; j < 8; ++j) ones[j] = (bf16_t)1.0f;

    floatx4 o[2][8] = {};
    floatx4 lac[2] = {};

#define STAGE_KN(buf, s0)                                                                \
    do {                                                                                 \
        _Pragma("unroll")                                                                \
        for (int it = 0; it < 6; ++it) {                                                 \
            int slot = it * 256 + tid;                                                   \
            int kk = slot >> 8, s = (slot >> 2) & 63, cc = slot & 3;                     \
            gload16((const char*)(kfull + ((size_t)h * T_TOK + (s0) + s) * 192 +         \
                                  kk * 32 + cc * 8),                                     \
                    (char*)kn2[buf] + slot * 16);                                        \
        }                                                                                \
    } while (0)

#define STAGE_VT(s0)                                                                     \
    do {                                                                                 \
        _Pragma("unroll")                                                                \
        for (int it = 0; it < 4; ++it) {                                                 \
            int slot = it * 256 + tid;                                                   \
            int ks = slot >> 9, d = (slot >> 2) & 127, cc = slot & 3;                    \
            gload16((const char*)(vT + ((size_t)h * 128 + d) * T_TOK + (s0) +            \
                                  ks * 32 + cc * 8),                                     \
                    (char*)vt2 + slot * 16);                                             \
        }                                                                                \
    } while (0)

    STAGE_KN(0, sBeg * 64);
    STAGE_VT(sBeg * 64);

    for (int si = sBeg; si < sEnd; ++si) {
        const int s0 = si * 64;
        const int buf = (si - sBeg) & 1;
        __syncthreads();                                    // kn[buf] + vt ready
        if (si + 1 < sEnd) STAGE_KN(buf ^ 1, s0 + 64);      // prefetch next K

        // ---- S = Q K^T (B-frags shared across strips) ----
        floatx4 s_acc[2][4] = {};
#pragma unroll
        for (int ni = 0; ni < 4; ++ni) {
#pragma unroll
            for (int kk = 0; kk < 6; ++kk) {
                bf16x8 b = *(const bf16x8*)(kn2[buf] + kk * 2048 +
                                            (ni * 16 + l15) * 32 + quad * 8);
                s_acc[0][ni] = MFMA_BF16(qf[0][kk], b, s_acc[0][ni]);
                s_acc[1][ni] = MFMA_BF16(qf[1][kk], b, s_acc[1][ni]);
            }
        }

        // ---- p = exp2(s*C1 - C2), masked; store to swizzled p_s ----
        const bool diag = (si >= 2 * qt);
#pragma unroll
        for (int st = 0; st < 2; ++st)
#pragma unroll
            for (int ni = 0; ni < 4; ++ni)
#pragma unroll
                for (int r = 0; r < 4; ++r) {
                    int prow = w * 32 + st * 16 + quad * 4 + r;
                    int pcol = ni * 16 + l15;
                    float pv = exp2f(s_acc[st][ni][r] * EXP_C1 - EXP_C2);
                    if (diag && (s0 + pcol) > (q0 + prow)) pv = 0.f;
                    p_s[prow * 64 + ((((pcol >> 3) ^ (prow & 7))) << 3) + (pcol & 7)] =
                        (bf16_t)pv;
                }

        // ---- O += P V ; l += P @ ones  (p_s rows wave-private) ----
#pragma unroll
        for (int ks = 0; ks < 2; ++ks) {
            bf16x8 a0, a1;
            {
                int arow = w * 32 + l15;
                a0 = *(const bf16x8*)(p_s + arow * 64 +
                                      (((ks * 4 + quad) ^ (arow & 7)) << 3));
                arow += 16;
                a1 = *(const bf16x8*)(p_s + arow * 64 +
                                      (((ks * 4 + quad) ^ (arow & 7)) << 3));
            }
            lac[0] = MFMA_BF16(a0, ones, lac[0]);
            lac[1] = MFMA_BF16(a1, ones, lac[1]);
#pragma unroll
            for (int ni = 0; ni < 8; ++ni) {
                bf16x8 b = *(const bf16x8*)(vt2 + ks * 4096 +
                                            (ni * 16 + l15) * 32 + quad * 8);
                o[0][ni] = MFMA_BF16(a0, b, o[0][ni]);
                o[1][ni] = MFMA_BF16(a1, b, o[1][ni]);
            }
        }
        __syncthreads();                                    // all waves done with vt
        if (si + 1 < sEnd) STAGE_VT(s0 + 64);               // stage next V
    }

    // ---- write partials: o (bf16, unnormalized) + l (fp32) ----
    const size_t pbase = ((size_t)c * 256 + unit) * 128;
#pragma unroll
    for (int st = 0; st < 2; ++st) {
#pragma unroll
        for (int ni = 0; ni < 8; ++ni)
#pragma unroll
            for (int r = 0; r < 4; ++r) {
                int lrow = w * 32 + st * 16 + quad * 4 + r;
                o_part[(pbase + lrow) * 128 + ni * 16 + l15] = (bf16_t)o[st][ni][r];
            }
        if (l15 == 0)
#pragma unroll
            for (int r = 0; r < 4; ++r) {
                int lrow = w * 32 + st * 16 + quad * 4 + r;
                l_part[pbase + lrow] = lac[st][r];
            }
    }
#undef STAGE_KN
#undef STAGE_VT
}

// ---------------------------------------------------------------------------
// Combine: attn_o = (o0 + o1) / (l0 + l1)   (no max bookkeeping needed)
// ---------------------------------------------------------------------------
__global__ void attn_combine(const bf16_t* __restrict__ o_part,
                             const float* __restrict__ l_part,
                             bf16_t* __restrict__ attn_o)
{
    int idx = blockIdx.x * 256 + threadIdx.x;   // t*256 + col-group (8 cols each)
    int t = idx >> 8, cg = idx & 255;
    int col = cg * 8;
    int h = col >> 7, d = col & 127;
    int qt = t >> 7, lrow = t & 127;
    size_t unit = (size_t)qt * 16 + h;
    size_t p0 = unit * 128 + lrow, p1 = (256 + unit) * 128 + lrow;
    float inv = 1.f / (l_part[p0] + l_part[p1]);
    bf16x8 a0 = *(const bf16x8*)(o_part + p0 * 128 + d);
    bf16x8 a1 = *(const bf16x8*)(o_part + p1 * 128 + d);
    bf16x8 out;
#pragma unroll
    for (int j = 0; j < 8; ++j)
        out[j] = (bf16_t)(((float)a0[j] + (float)a1[j]) * inv);
    *(bf16x8*)(attn_o + (size_t)t * (NH * D_V) + col) = out;
}

// ---------------------------------------------------------------------------
extern "C" void kernel_launch(void* const* d_in, const int* in_sizes, int n_in,
                              void* d_out, int out_size, void* d_ws, size_t ws_size,
                              hipStream_t stream) {
    const float* hidden = (const float*)d_in[0];
    const int* positions = (const int*)d_in[1];
    const float* w_qkv_a = (const float*)d_in[2];
    const float* g_q = (const float*)d_in[3];
    const float* w_q_b = (const float*)d_in[4];
    const float* g_kv = (const float*)d_in[5];
    const float* w_kv_b = (const float*)d_in[6];
    const float* w_o = (const float*)d_in[7];
    float* out = (float*)d_out;

    // ---- workspace layout (~94.5 MB) ----
    char* p = (char*)d_ws;
    float* qkv_a = (float*)p;                       // [2048][2176] fp32
    bf16_t* attn_o = (bf16_t*)p;                    // alias (qkv_a dead by then)
    p += (size_t)T_TOK * QKV_NPAD * 4;
    bf16_t* hbf = (bf16_t*)p;                       // [2048][2048] bf16
    bf16_t* qn = hbf;                               // alias after GEMM1
    bf16_t* kvn = hbf + (size_t)T_TOK * Q_LORA;
    p += (size_t)T_TOK * HID * 2;
    bf16_t* qbuf = (bf16_t*)p;  p += (size_t)T_TOK * NH * D_QK * 2;   // [2048][3072]
    bf16_t* vtmp = (bf16_t*)p;  p += (size_t)T_TOK * NH * D_V * 2;    // [2048][2048]
    bf16_t* kfull = (bf16_t*)p; p += (size_t)NH * T_TOK * 192 * 2;    // [16][2048][192]
    bf16_t* vT = (bf16_t*)p;    p += (size_t)NH * 128 * T_TOK * 2;    // [16][128][2048]
    bf16_t* wt_qkv_a = (bf16_t*)p; p += (size_t)QKV_NPAD * HID * 2;   // [2176][2048]
    bf16_t* wt_q_b = (bf16_t*)p;   p += (size_t)3072 * Q_LORA * 2;    // [3072][1536]
    bf16_t* wt_kv_b = (bf16_t*)p;  p += (size_t)4096 * KV_LORA * 2;   // [4096][512]
    bf16_t* wt_o = (bf16_t*)p;                                        // [2048][2048]

    // attn partials OVERLAY wt_qkv_a + wt_q_b (dead before attn):
    //   o_part bf16 [2][256][128][128] = 16.78 MB ; l fp32 [2][256][128] = 256 KB
    bf16_t* o_part = wt_qkv_a;
    float* l_part = (float*)(o_part + (size_t)2 * 256 * 128 * 128);

    dim3 tb(32, 8);

    // 0. dtype prep
    cvt_f2b<<<(T_TOK * HID) / 256, 256, 0, stream>>>(hidden, hbf, T_TOK * HID);
    transpose_all<<<dim3(128, 64, 4), tb, 0, stream>>>(
        w_qkv_a, w_q_b, w_kv_b, w_o, wt_qkv_a, wt_q_b, wt_kv_b, wt_o);

    // 1. qkv_a = hidden @ w_qkv_a
    gemm_mfma<0><<<dim3(QKV_NPAD / 128, T_TOK / 128), 256, 0, stream>>>(
        hbf, wt_qkv_a, qkv_a, nullptr, nullptr, nullptr, T_TOK, QKV_NPAD, HID);

    // 2. fused rmsnorm + gains + rope(k_pe)->kfull (all heads)
    mid_fuse<<<T_TOK, 256, 0, stream>>>(qkv_a, positions, g_q, g_kv, qn, kvn, kfull);

    // 3. q = qn @ w_q_b ; rope in place   (wt_qkv_a dead after gemm1)
    gemm_mfma<1><<<dim3(3072 / 128, T_TOK / 128), 256, 0, stream>>>(
        qn, wt_q_b, nullptr, qbuf, nullptr, nullptr, T_TOK, 3072, Q_LORA);
    rope_q_kernel<<<(T_TOK * NH * 32) / 256, 256, 0, stream>>>(qbuf, positions);

    // 4. kv GEMM -> kfull(nope part) + vtmp; vtmp -> vT   (wt_q_b dead after)
    gemm_mfma<2><<<dim3(4096 / 128, T_TOK / 128), 256, 0, stream>>>(
        kvn, wt_kv_b, nullptr, nullptr, kfull, vtmp, T_TOK, 4096, KV_LORA);
    transpose_b2b<<<dim3(HID / 32, T_TOK / 32), tb, 0, stream>>>(vtmp, vT, T_TOK, HID);

    // 5. flash attention: balanced split-s partials (512 blocks) + combine
    attn_part<<<512, 256, 0, stream>>>(qbuf, kfull, vT, o_part, l_part);
    attn_combine<<<(T_TOK * 256) / 256, 256, 0, stream>>>(o_part, l_part, attn_o);

    // 6. out = attn_o @ w_o
    gemm_mfma<0><<<dim3(HID / 128, T_TOK / 128), 256, 0, stream>>>(
        attn_o, wt_o, out, nullptr, nullptr, nullptr, T_TOK, HID, NH * D_V);
}